// Round 15
// baseline (810.288 us; speedup 1.0000x reference)
//
#include <hip/hip_runtime.h>
#include <hip/hip_bf16.h>
#include <math.h>

// DualMAR: 2-layer weighted GCN over 100K nodes / 3.2M edges + code/visit
// attention + MLP decoder.
// R14: L2 working-set experiment on agg. Each agg split into two D-half
// passes (pass p gathers 256B sub-rows at byte offset p*256) -> gather table
// working set 25.6MB/pass vs 51.2MB. Tests whether the measured 55% L2 hit
// rate is capacity-driven. Pre-commit: FETCH sum unchanged => revert + declare
// roofline. Everything else identical to R13.

#define D 256
#define BPAT 64
#define VIS 50
#define CODES 64
#define NEG_INF -1e9f
#define MPAD 100096   // 782 * 128
#define BINB 32       // dsts per bin
#define NBIN 3125     // 3125 * 32 = 100000 exactly
#define SORTCAP 1536  // LDS staging capacity in binsort (bin avg 1024)

typedef unsigned short ushort_t;
typedef short short8 __attribute__((ext_vector_type(8)));
typedef float f32x4 __attribute__((ext_vector_type(4)));

__device__ __forceinline__ float blo(unsigned u) { return __uint_as_float(u << 16); }
__device__ __forceinline__ float bhi(unsigned u) { return __uint_as_float(u & 0xffff0000u); }
__device__ __forceinline__ float bf2f(ushort_t u) { return __uint_as_float((unsigned)u << 16); }
__device__ __forceinline__ ushort_t f2bfu(float f) {
    __hip_bfloat16 h = __float2bfloat16(f);
    return *reinterpret_cast<ushort_t*>(&h);
}
__device__ __forceinline__ unsigned pack2(float a, float b) {
    return (unsigned)f2bfu(a) | ((unsigned)f2bfu(b) << 16);
}
__device__ __forceinline__ float fast_tanh(float x) {
    return 1.f - 2.f / (__expf(2.f * x) + 1.f);
}

// -------- fused: bin histogram (blocks 0..255) + 4x weight transpose --------
__global__ __launch_bounds__(512) void count_transpose_kernel(
    const int* __restrict__ ei, int* __restrict__ bincount, int ne,
    const float* __restrict__ Wa, const float* __restrict__ Wb,
    const float* __restrict__ Wc, const float* __restrict__ Wd,
    ushort_t* __restrict__ Ta, ushort_t* __restrict__ Tb,
    ushort_t* __restrict__ Tc, ushort_t* __restrict__ Td) {
    __shared__ int h[NBIN];
    __shared__ float tt[2][32][33];
    if (blockIdx.x < 256) {
        for (int i = threadIdx.x; i < NBIN; i += 512) h[i] = 0;
        __syncthreads();
        const int stride = 256 * 512;
        for (int e = blockIdx.x * 512 + threadIdx.x; e < ne; e += stride)
            atomicAdd(&h[ei[(size_t)ne + e] >> 5], 1);
        __syncthreads();
        for (int i = threadIdx.x; i < NBIN; i += 512) {
            int c = h[i];
            if (c) atomicAdd(&bincount[i], c);
        }
    } else {
        int tile = (blockIdx.x - 256) * 2 + (threadIdx.x >> 8);
        int which = tile >> 6, rem = tile & 63;
        int bx = (rem & 7) << 5, by = (rem >> 3) << 5;
        const float* W = (which == 0) ? Wa : (which == 1) ? Wb
                        : (which == 2) ? Wc : Wd;
        ushort_t* Wt = (which == 0) ? Ta : (which == 1) ? Tb
                      : (which == 2) ? Tc : Td;
        int hf = threadIdx.x >> 8;
        int ltid = threadIdx.x & 255;
        int lx = ltid & 31, ly = ltid >> 5;
        #pragma unroll
        for (int i = 0; i < 32; i += 8)
            tt[hf][ly + i][lx] = W[(size_t)(by + ly + i) * 256 + bx + lx];
        __syncthreads();
        #pragma unroll
        for (int i = 0; i < 32; i += 8)
            Wt[(size_t)(bx + ly + i) * 256 + by + lx] = f2bfu(tt[hf][lx][ly + i]);
    }
}

__global__ __launch_bounds__(64) void bin_scan_kernel(
    const int* __restrict__ bincount, int* __restrict__ binstart,
    int* __restrict__ bincursor, int* __restrict__ rp, int ne, int nn) {
    __shared__ int carry;
    int lane = threadIdx.x;
    if (lane == 0) carry = 0;
    __syncthreads();
    for (int base = 0; base < NBIN; base += 64) {
        int i = base + lane;
        int v = (i < NBIN) ? bincount[i] : 0;
        int x = v;
        #pragma unroll
        for (int d = 1; d < 64; d <<= 1) {
            int y = __shfl_up(x, (unsigned)d, 64);
            if (lane >= d) x += y;
        }
        int c = carry;
        if (i < NBIN) { int ex = c + x - v; binstart[i] = ex; bincursor[i] = ex; }
        __syncthreads();
        if (lane == 63) carry = c + x;
        __syncthreads();
    }
    if (lane == 0) { binstart[NBIN] = ne; rp[nn] = ne; }
}

// -------- fused: partition (blocks 0..255) + gemm_f32a (blocks 256..1037) ---
__global__ __launch_bounds__(512) void part_gemm_kernel(
    const int* __restrict__ ei, const float* __restrict__ ew,
    int* __restrict__ bincursor, uint2* __restrict__ ptmp, int ne,
    const float* __restrict__ Af, const ushort_t* __restrict__ Wt,
    ushort_t* __restrict__ out, int nvalid) {
    __shared__ int h[NBIN];
    __shared__ int base_[NBIN];
    __shared__ __align__(16) ushort_t As[128 * 32];
    __shared__ __align__(16) ushort_t Bs[256 * 32];
    const int tid = threadIdx.x;
    if (blockIdx.x < 256) {
        for (int i = tid; i < NBIN; i += 512) h[i] = 0;
        __syncthreads();
        const int stride = 256 * 512;
        for (int e = blockIdx.x * 512 + tid; e < ne; e += stride)
            atomicAdd(&h[ei[(size_t)ne + e] >> 5], 1);
        __syncthreads();
        for (int i = tid; i < NBIN; i += 512) {
            int c = h[i];
            base_[i] = c ? atomicAdd(&bincursor[i], c) : 0;
            h[i] = 0;
        }
        __syncthreads();
        for (int e = blockIdx.x * 512 + tid; e < ne; e += stride) {
            int dd = ei[(size_t)ne + e];
            int ss = ei[e];
            float w = ew[e];
            int bin = dd >> 5;
            int r = atomicAdd(&h[bin], 1);
            ptmp[base_[bin] + r] =
                make_uint2((unsigned)ss | ((unsigned)(dd & 31) << 17),
                           __float_as_uint(w));
        }
        return;
    }
    const int gbid = blockIdx.x - 256;
    const int lane = tid & 63;
    const int wv = tid >> 6;
    const int wr = wv >> 2, wc = wv & 3;
    const size_t brow = (size_t)gbid * 128;

    const int ra = tid >> 2, ca = tid & 3;
    const int rb1 = ra + 128;
    const int csa = ca ^ ((ra >> 1) & 3);
    const int arow = (int)brow + ra;
    const bool aval = arow < nvalid;
    const float* gAf = Af + (size_t)arow * 256 + ca * 8;
    const ushort_t* gB0 = Wt + (size_t)ra  * 256 + ca * 8;
    const ushort_t* gB1 = Wt + (size_t)rb1 * 256 + ca * 8;
    ushort_t* lA  = As + ra * 32 + csa * 8;
    ushort_t* lB0 = Bs + ra * 32 + csa * 8;
    ushort_t* lB1 = Bs + rb1 * 32 + csa * 8;

    const int g = lane >> 4, rl = lane & 15;
    int aoff[4], boff[4];
    #pragma unroll
    for (int m = 0; m < 4; ++m) {
        int row = wr * 64 + m * 16 + rl;
        aoff[m] = row * 32 + (g ^ ((row >> 1) & 3)) * 8;
    }
    #pragma unroll
    for (int n = 0; n < 4; ++n) {
        int row = wc * 64 + n * 16 + rl;
        boff[n] = row * 32 + (g ^ ((row >> 1) & 3)) * 8;
    }

    f32x4 acc[4][4] = {};
    float4 pa0 = make_float4(0.f, 0.f, 0.f, 0.f), pa1 = pa0;
    if (aval) { pa0 = *(const float4*)gAf; pa1 = *(const float4*)(gAf + 4); }
    uint4 vb0 = *(const uint4*)gB0;
    uint4 vb1 = *(const uint4*)gB1;

    for (int ks = 0; ks < 8; ++ks) {
        uint4 va;
        va.x = pack2(pa0.x, pa0.y); va.y = pack2(pa0.z, pa0.w);
        va.z = pack2(pa1.x, pa1.y); va.w = pack2(pa1.z, pa1.w);
        *(uint4*)lA = va; *(uint4*)lB0 = vb0; *(uint4*)lB1 = vb1;
        __syncthreads();
        if (ks < 7) {
            int k0 = (ks + 1) * 32;
            if (aval) {
                pa0 = *(const float4*)(gAf + k0);
                pa1 = *(const float4*)(gAf + k0 + 4);
            }
            vb0 = *(const uint4*)(gB0 + k0);
            vb1 = *(const uint4*)(gB1 + k0);
        }
        short8 af[4], bfv[4];
        #pragma unroll
        for (int m = 0; m < 4; ++m) af[m] = *(const short8*)(As + aoff[m]);
        #pragma unroll
        for (int n = 0; n < 4; ++n) bfv[n] = *(const short8*)(Bs + boff[n]);
        #pragma unroll
        for (int m = 0; m < 4; ++m)
            #pragma unroll
            for (int n = 0; n < 4; ++n)
                acc[m][n] = __builtin_amdgcn_mfma_f32_16x16x32_bf16(
                    af[m], bfv[n], acc[m][n], 0, 0, 0);
        __syncthreads();
    }

    #pragma unroll
    for (int m = 0; m < 4; ++m) {
        #pragma unroll
        for (int r = 0; r < 4; ++r) {
            size_t row = brow + wr * 64 + m * 16 + g * 4 + r;
            #pragma unroll
            for (int n = 0; n < 4; ++n) {
                int col = wc * 64 + n * 16 + rl;
                out[row * 256 + col] = f2bfu(acc[m][n][r]);
            }
        }
    }
}

// within-bin counting sort -> dst-sorted (src,w) + rp[] CSR
__global__ __launch_bounds__(256) void binsort_kernel(
    const uint2* __restrict__ ptmp, const int* __restrict__ binstart,
    uint2* __restrict__ epair, int* __restrict__ rp) {
    int b = blockIdx.x;
    int tid = threadIdx.x;
    int beg = binstart[b], end = binstart[b + 1];
    int nE = end - beg;
    __shared__ uint2 sbuf[SORTCAP];
    __shared__ int cnt[BINB];
    __shared__ int cur[BINB];
    if (tid < BINB) cnt[tid] = 0;
    __syncthreads();
    if (nE <= SORTCAP) {
        for (int i = tid; i < nE; i += 256) {
            uint2 p = ptmp[beg + i];
            sbuf[i] = p;
            atomicAdd(&cnt[(p.x >> 17) & 31], 1);
        }
        __syncthreads();
        if (tid < BINB) {
            int v = cnt[tid];
            int x = v;
            #pragma unroll
            for (int d = 1; d < BINB; d <<= 1) {
                int y = __shfl_up(x, (unsigned)d, BINB);
                if (tid >= d) x += y;
            }
            int start = beg + x - v;
            cur[tid] = start;
            rp[b * BINB + tid] = start;
        }
        __syncthreads();
        for (int i = tid; i < nE; i += 256) {
            uint2 p = sbuf[i];
            int dl = (p.x >> 17) & 31;
            int pos = atomicAdd(&cur[dl], 1);
            epair[pos] = make_uint2(p.x & 0x1FFFF, p.y);
        }
    } else {
        for (int i = beg + tid; i < end; i += 256)
            atomicAdd(&cnt[(ptmp[i].x >> 17) & 31], 1);
        __syncthreads();
        if (tid < BINB) {
            int v = cnt[tid];
            int x = v;
            #pragma unroll
            for (int d = 1; d < BINB; d <<= 1) {
                int y = __shfl_up(x, (unsigned)d, BINB);
                if (tid >= d) x += y;
            }
            int start = beg + x - v;
            cur[tid] = start;
            rp[b * BINB + tid] = start;
        }
        __syncthreads();
        for (int i = beg + tid; i < end; i += 256) {
            uint2 p = ptmp[i];
            int dl = (p.x >> 17) & 31;
            int pos = atomicAdd(&cur[dl], 1);
            epair[pos] = make_uint2(p.x & 0x1FFFF, p.y);
        }
    }
}

// ------------- weighted aggregation, D-half pass (L2 working-set probe) ----
// PASS p gathers bytes [p*256, p*256+256) of each src row: 25.6MB working set.
// One wave per dst row; two 32-lane halves gather different edges, 8B/lane.
__device__ __forceinline__ void acc4(float* a, uint2 v, float w) {
    a[0] += w * blo(v.x); a[1] += w * bhi(v.x);
    a[2] += w * blo(v.y); a[3] += w * bhi(v.y);
}

template<int ACT, int PASS>
__global__ __launch_bounds__(256) void agg_half_kernel(
    const ushort_t* __restrict__ x, const int* __restrict__ rp,
    const uint2* __restrict__ ep, const float* __restrict__ bias,
    ushort_t* __restrict__ out, int n) {
    int wv = (int)(((size_t)blockIdx.x * blockDim.x + threadIdx.x) >> 6);
    int lane = threadIdx.x & 63;
    if (wv >= n) return;
    int half = lane >> 5;
    int l32 = lane & 31;
    int beg = rp[wv], end = rp[wv + 1];
    const ushort_t* xh = x + PASS * 128;   // D-half base
    float a[4] = {};
    int e = beg;
    for (; e + 16 <= end; e += 16) {
        uint2 p0 = ep[e + half];
        uint2 p1 = ep[e + 2 + half];
        uint2 p2 = ep[e + 4 + half];
        uint2 p3 = ep[e + 6 + half];
        uint2 p4 = ep[e + 8 + half];
        uint2 p5 = ep[e + 10 + half];
        uint2 p6 = ep[e + 12 + half];
        uint2 p7 = ep[e + 14 + half];
        uint2 v0 = ((const uint2*)(xh + (size_t)p0.x * D))[l32];
        uint2 v1 = ((const uint2*)(xh + (size_t)p1.x * D))[l32];
        uint2 v2 = ((const uint2*)(xh + (size_t)p2.x * D))[l32];
        uint2 v3 = ((const uint2*)(xh + (size_t)p3.x * D))[l32];
        uint2 v4 = ((const uint2*)(xh + (size_t)p4.x * D))[l32];
        uint2 v5 = ((const uint2*)(xh + (size_t)p5.x * D))[l32];
        uint2 v6 = ((const uint2*)(xh + (size_t)p6.x * D))[l32];
        uint2 v7 = ((const uint2*)(xh + (size_t)p7.x * D))[l32];
        acc4(a, v0, __uint_as_float(p0.y));
        acc4(a, v1, __uint_as_float(p1.y));
        acc4(a, v2, __uint_as_float(p2.y));
        acc4(a, v3, __uint_as_float(p3.y));
        acc4(a, v4, __uint_as_float(p4.y));
        acc4(a, v5, __uint_as_float(p5.y));
        acc4(a, v6, __uint_as_float(p6.y));
        acc4(a, v7, __uint_as_float(p7.y));
    }
    for (; e + 4 <= end; e += 4) {
        uint2 p0 = ep[e + half];
        uint2 p1 = ep[e + 2 + half];
        uint2 v0 = ((const uint2*)(xh + (size_t)p0.x * D))[l32];
        uint2 v1 = ((const uint2*)(xh + (size_t)p1.x * D))[l32];
        acc4(a, v0, __uint_as_float(p0.y));
        acc4(a, v1, __uint_as_float(p1.y));
    }
    for (; e + 2 <= end; e += 2) {
        uint2 p0 = ep[e + half];
        uint2 v0 = ((const uint2*)(xh + (size_t)p0.x * D))[l32];
        acc4(a, v0, __uint_as_float(p0.y));
    }
    if (e < end) {
        uint2 p0 = ep[e];
        uint2 v0 = ((const uint2*)(xh + (size_t)p0.x * D))[l32];
        acc4(a, v0, half ? 0.f : __uint_as_float(p0.y));
    }
    #pragma unroll
    for (int j = 0; j < 4; ++j) a[j] += __shfl_xor(a[j], 32, 64);
    if (half == 0) {
        float4 b0 = ((const float4*)(bias + PASS * 128))[l32];
        a[0] += b0.x; a[1] += b0.y; a[2] += b0.z; a[3] += b0.w;
        if (ACT == 1) {
            #pragma unroll
            for (int j = 0; j < 4; ++j) a[j] = fmaxf(a[j], 0.f);
        }
        uint2 o;
        o.x = pack2(a[0], a[1]); o.y = pack2(a[2], a[3]);
        ((uint2*)(out + (size_t)wv * D + PASS * 128))[l32] = o;
    }
}

// ---------------- bf16 MFMA GEMM: MODE 1 plain, MODE 2 tanh-dot -------
template<int MODE>
__global__ __launch_bounds__(512) void mfma_gemm_kernel(
    const ushort_t* __restrict__ A, const ushort_t* __restrict__ Wt,
    const float* __restrict__ bias, ushort_t* __restrict__ out,
    const float* __restrict__ u, float* __restrict__ tout, int mvalid) {
    __shared__ __align__(16) ushort_t As[128 * 32];
    __shared__ __align__(16) ushort_t Bs[256 * 32];
    __shared__ float s_t[128];
    const int tid = threadIdx.x;
    const int lane = tid & 63;
    const int wv = tid >> 6;
    const int wr = wv >> 2, wc = wv & 3;
    const size_t brow = (size_t)blockIdx.x * 128;

    const int ra = tid >> 2, ca = tid & 3;
    const int rb1 = ra + 128;
    const int csa = ca ^ ((ra >> 1) & 3);
    const ushort_t* gA  = A  + (brow + ra) * 256 + ca * 8;
    const ushort_t* gB0 = Wt + (size_t)ra  * 256 + ca * 8;
    const ushort_t* gB1 = Wt + (size_t)rb1 * 256 + ca * 8;
    ushort_t* lA  = As + ra * 32 + csa * 8;
    ushort_t* lB0 = Bs + ra * 32 + csa * 8;
    ushort_t* lB1 = Bs + rb1 * 32 + csa * 8;

    const int g = lane >> 4, rl = lane & 15;
    int aoff[4], boff[4];
    #pragma unroll
    for (int m = 0; m < 4; ++m) {
        int row = wr * 64 + m * 16 + rl;
        aoff[m] = row * 32 + (g ^ ((row >> 1) & 3)) * 8;
    }
    #pragma unroll
    for (int n = 0; n < 4; ++n) {
        int row = wc * 64 + n * 16 + rl;
        boff[n] = row * 32 + (g ^ ((row >> 1) & 3)) * 8;
    }

    if (MODE == 2 && tid < 128) s_t[tid] = 0.f;

    f32x4 acc[4][4] = {};
    uint4 va  = *(const uint4*)gA;
    uint4 vb0 = *(const uint4*)gB0;
    uint4 vb1 = *(const uint4*)gB1;

    for (int ks = 0; ks < 8; ++ks) {
        *(uint4*)lA = va; *(uint4*)lB0 = vb0; *(uint4*)lB1 = vb1;
        __syncthreads();
        if (ks < 7) {
            int k0 = (ks + 1) * 32;
            va  = *(const uint4*)(gA + k0);
            vb0 = *(const uint4*)(gB0 + k0);
            vb1 = *(const uint4*)(gB1 + k0);
        }
        short8 af[4], bfv[4];
        #pragma unroll
        for (int m = 0; m < 4; ++m) af[m] = *(const short8*)(As + aoff[m]);
        #pragma unroll
        for (int n = 0; n < 4; ++n) bfv[n] = *(const short8*)(Bs + boff[n]);
        #pragma unroll
        for (int m = 0; m < 4; ++m)
            #pragma unroll
            for (int n = 0; n < 4; ++n)
                acc[m][n] = __builtin_amdgcn_mfma_f32_16x16x32_bf16(
                    af[m], bfv[n], acc[m][n], 0, 0, 0);
        __syncthreads();
    }

    if (MODE == 2) {
        float uvv[4];
        #pragma unroll
        for (int n = 0; n < 4; ++n) uvv[n] = u[wc * 64 + n * 16 + rl];
        #pragma unroll
        for (int m = 0; m < 4; ++m) {
            #pragma unroll
            for (int r = 0; r < 4; ++r) {
                float v = 0.f;
                #pragma unroll
                for (int n = 0; n < 4; ++n) v += fast_tanh(acc[m][n][r]) * uvv[n];
                v += __shfl_xor(v, 1, 64);
                v += __shfl_xor(v, 2, 64);
                v += __shfl_xor(v, 4, 64);
                v += __shfl_xor(v, 8, 64);
                if (rl == 0) atomicAdd(&s_t[wr * 64 + m * 16 + g * 4 + r], v);
            }
        }
        __syncthreads();
        if (tid < 128 && brow + tid < (size_t)mvalid) tout[brow + tid] = s_t[tid];
    } else {
        #pragma unroll
        for (int m = 0; m < 4; ++m) {
            #pragma unroll
            for (int r = 0; r < 4; ++r) {
                size_t row = brow + wr * 64 + m * 16 + g * 4 + r;
                #pragma unroll
                for (int n = 0; n < 4; ++n) {
                    int col = wc * 64 + n * 16 + rl;
                    float v = acc[m][n][r] + (bias ? bias[col] : 0.f);
                    out[row * 256 + col] = f2bfu(v);
                }
            }
        }
    }
}

// ---------------- code attention (branchless gather) ----------------
__global__ __launch_bounds__(256) void code_attn_kernel(
    const int* __restrict__ codes, const float* __restrict__ t,
    const ushort_t* __restrict__ emb, ushort_t* __restrict__ vembB,
    int* __restrict__ vmask) {
    int bv = blockIdx.x;
    int tid = threadIdx.x;
    __shared__ int s_codes[CODES];
    __shared__ float s_av[CODES];
    __shared__ int s_valid;
    if (tid < 64) {
        int c = codes[(size_t)bv * CODES + tid];
        s_codes[tid] = c;
        float e = (c > 0) ? t[c] : NEG_INF;
        float m = e;
        #pragma unroll
        for (int d = 32; d; d >>= 1) m = fmaxf(m, __shfl_xor(m, d, 64));
        float ex = expf(e - m);   // invalid codes underflow to exactly 0
        float s = ex;
        #pragma unroll
        for (int d = 32; d; d >>= 1) s += __shfl_xor(s, d, 64);
        s_av[tid] = ex / s;
        if (tid == 0) s_valid = (m > -1e8f) ? 1 : 0;
    }
    __syncthreads();
    float acc = 0.f;
    #pragma unroll 8
    for (int c = 0; c < CODES; ++c)
        acc += s_av[c] * bf2f(emb[(size_t)s_codes[c] * D + tid]);
    int valid = s_valid;
    vembB[(size_t)bv * D + tid] = f2bfu(valid ? acc : 0.f);
    if (tid == 0) vmask[bv] = valid;
}

// -------- fused patient attention + 3-layer decoder (one block per patient)
__global__ __launch_bounds__(512) void patient_dec_kernel(
    const ushort_t* __restrict__ vembB, const float* __restrict__ epr,
    const int* __restrict__ vmask,
    const float* __restrict__ Wd1, const float* __restrict__ bd1,
    const float* __restrict__ Wd2, const float* __restrict__ bd2,
    const float* __restrict__ Wd3, const float* __restrict__ bd3,
    float* __restrict__ outp) {
    int b = blockIdx.x;
    int tid = threadIdx.x;
    __shared__ float s_ap[VIS];
    __shared__ float s_x[256];
    __shared__ float s_h1[512];
    __shared__ float s_h2[256];
    __shared__ int s_any;

    if (tid < 64) {
        float e = -3e38f;
        if (tid < VIS) e = vmask[b * VIS + tid] ? epr[b * VIS + tid] : NEG_INF;
        float m = e;
        #pragma unroll
        for (int d = 32; d; d >>= 1) m = fmaxf(m, __shfl_xor(m, d, 64));
        float ex = (tid < VIS) ? expf(e - m) : 0.f;
        float s = ex;
        #pragma unroll
        for (int d = 32; d; d >>= 1) s += __shfl_xor(s, d, 64);
        if (tid < VIS) s_ap[tid] = ex / s;
        if (tid == 0) s_any = (m > -1e8f) ? 1 : 0;
    }
    __syncthreads();
    if (tid < 256) {
        float acc = 0.f;
        for (int v = 0; v < VIS; ++v)
            acc += s_ap[v] * bf2f(vembB[((size_t)b * VIS + v) * D + tid]);
        s_x[tid] = s_any ? acc : 0.f;
    }
    __syncthreads();
    {
        float acc = bd1[tid];
        #pragma unroll 8
        for (int k = 0; k < 256; ++k)
            acc = fmaf(s_x[k], Wd1[(size_t)k * 512 + tid], acc);
        s_h1[tid] = fmaxf(acc, 0.f);
    }
    __syncthreads();
    if (tid < 256) {
        float acc = bd2[tid];
        #pragma unroll 8
        for (int k = 0; k < 512; ++k)
            acc = fmaf(s_h1[k], Wd2[(size_t)k * 256 + tid], acc);
        s_h2[tid] = fmaxf(acc, 0.f);
    }
    __syncthreads();
    for (int j = tid; j < 1000; j += 512) {
        float acc = bd3[j];
        #pragma unroll 8
        for (int k = 0; k < 256; ++k)
            acc = fmaf(s_h2[k], Wd3[(size_t)k * 1000 + j], acc);
        outp[(size_t)b * 1000 + j] = acc;
    }
}

extern "C" void kernel_launch(void* const* d_in, const int* in_sizes, int n_in,
                              void* d_out, int out_size, void* d_ws, size_t ws_size,
                              hipStream_t stream) {
    const int* edge_index    = (const int*)d_in[0];
    const float* edge_weight = (const float*)d_in[1];
    const int* codes         = (const int*)d_in[2];
    const float* node_emb    = (const float*)d_in[3];
    const float* W1 = (const float*)d_in[4];
    const float* b1 = (const float*)d_in[5];
    const float* W2 = (const float*)d_in[6];
    const float* b2 = (const float*)d_in[7];
    const float* Wv = (const float*)d_in[8];
    const float* uv = (const float*)d_in[9];
    const float* Wp = (const float*)d_in[10];
    const float* up = (const float*)d_in[11];
    const float* Wd1 = (const float*)d_in[12];
    const float* bd1 = (const float*)d_in[13];
    const float* Wd2 = (const float*)d_in[14];
    const float* bd2 = (const float*)d_in[15];
    const float* Wd3 = (const float*)d_in[16];
    const float* bd3 = (const float*)d_in[17];

    const int NE = in_sizes[1];          // 3,200,000
    const int NN = in_sizes[3] / D;      // 100,000

    char* ws = (char*)d_ws;
    size_t off = 0;
    auto alloc = [&](size_t bytes) -> void* {
        void* p = ws + off;
        off += (bytes + 255) & ~(size_t)255;
        return p;
    };
    ushort_t* zbuf = (ushort_t*)alloc((size_t)MPAD * D * 2);  // z1 / z2
    ushort_t* hbuf = (ushort_t*)alloc((size_t)MPAD * D * 2);  // h
    ushort_t* embB = (ushort_t*)alloc((size_t)MPAD * D * 2);  // emb (bf16)
    uint2* ptmp   = (uint2*)alloc((size_t)NE * 8);            // bin-partitioned
    uint2* epair  = (uint2*)alloc((size_t)NE * 8);            // dst-sorted (src,w)
    int* bincount = (int*)alloc((size_t)NBIN * 4);
    int* binstart = (int*)alloc((size_t)(NBIN + 1) * 4);
    int* bincursor= (int*)alloc((size_t)NBIN * 4);
    int* rp       = (int*)alloc((size_t)(NN + 1) * 4);
    ushort_t* W1t = (ushort_t*)alloc(256 * 256 * 2);
    ushort_t* W2t = (ushort_t*)alloc(256 * 256 * 2);
    ushort_t* Wvt = (ushort_t*)alloc(256 * 256 * 2);
    ushort_t* Wpt = (ushort_t*)alloc(256 * 256 * 2);
    float* tbuf  = (float*)alloc((size_t)NN * 4);
    ushort_t* vembB = (ushort_t*)alloc((size_t)BPAT * VIS * D * 2);
    int*   vmask = (int*)  alloc((size_t)BPAT * VIS * 4);
    float* epr   = (float*)alloc((size_t)BPAT * VIS * 4);
    (void)ws_size; (void)n_in; (void)out_size;

    const int ab = NN / 4;                    // one wave/row, 4 waves/block

    // --- CSR build + layer-1 GEMM (co-scheduled) ---
    hipMemsetAsync(bincount, 0, (size_t)NBIN * 4, stream);
    count_transpose_kernel<<<256 + 128, 512, 0, stream>>>(
        edge_index, bincount, NE, W1, W2, Wv, Wp, W1t, W2t, Wvt, Wpt);
    bin_scan_kernel<<<1, 64, 0, stream>>>(bincount, binstart, bincursor, rp, NE, NN);
    part_gemm_kernel<<<256 + MPAD / 128, 512, 0, stream>>>(
        edge_index, edge_weight, bincursor, ptmp, NE,
        node_emb, W1t, zbuf, NN);
    binsort_kernel<<<NBIN, 256, 0, stream>>>(ptmp, binstart, epair, rp);

    // --- GCN layer 1 (agg of z1, two D-half passes): h = relu(agg(z1)+b1) ---
    agg_half_kernel<1, 0><<<ab, 256, 0, stream>>>(zbuf, rp, epair, b1, hbuf, NN);
    agg_half_kernel<1, 1><<<ab, 256, 0, stream>>>(zbuf, rp, epair, b1, hbuf, NN);

    // --- GCN layer 2: z2 = h @ W2; emb = agg(z2) + b2 (two D-half passes) ---
    mfma_gemm_kernel<1><<<MPAD / 128, 512, 0, stream>>>(
        hbuf, W2t, nullptr, zbuf, nullptr, nullptr, 0);
    agg_half_kernel<0, 0><<<ab, 256, 0, stream>>>(zbuf, rp, epair, b2, embB, NN);
    agg_half_kernel<0, 1><<<ab, 256, 0, stream>>>(zbuf, rp, epair, b2, embB, NN);

    // --- fused per-node code score: t = tanh(emb @ Wv) @ uv ---
    mfma_gemm_kernel<2><<<MPAD / 128, 512, 0, stream>>>(
        embB, Wvt, nullptr, nullptr, uv, tbuf, NN);

    // --- code attention -> vemb (bf16) ---
    code_attn_kernel<<<BPAT * VIS, 256, 0, stream>>>(codes, tbuf, embB, vembB, vmask);

    // --- fused visit score: ep = tanh(vemb @ Wp) @ up ---
    mfma_gemm_kernel<2><<<BPAT * VIS / 128, 512, 0, stream>>>(
        vembB, Wpt, nullptr, nullptr, up, epr, BPAT * VIS);

    // --- fused patient attention + decoder MLP ---
    patient_dec_kernel<<<BPAT, 512, 0, stream>>>(
        vembB, epr, vmask, Wd1, bd1, Wd2, bd2, Wd3, bd3, (float*)d_out);
}

// Round 16
// 793.994 us; speedup vs baseline: 1.0205x; 1.0205x over previous
//
#include <hip/hip_runtime.h>
#include <hip/hip_bf16.h>
#include <math.h>

// DualMAR: 2-layer weighted GCN over 100K nodes / 3.2M edges + code/visit
// attention + MLP decoder.
// R15: revert of R14's D-half agg split (null per pre-commit: per-layer agg
// time unchanged, total +15us overhead) -> exact R13 structure restored.
// agg is at the random-512B-gather fabric roofline (~3.85 TB/s past-L2;
// byte-volume/MLP/occupancy/phase/working-set levers all measured null).
// Structure: binned partition -> binsort CSR -> [GEMM-first GCN layers via
// agg linearity, agg fused bias+relu] -> fused tanh-dot epilogues ->
// code attention -> fused patient-attention+decoder. 12 dispatches.

#define D 256
#define BPAT 64
#define VIS 50
#define CODES 64
#define NEG_INF -1e9f
#define MPAD 100096   // 782 * 128
#define BINB 32       // dsts per bin
#define NBIN 3125     // 3125 * 32 = 100000 exactly
#define SORTCAP 1536  // LDS staging capacity in binsort (bin avg 1024)

typedef unsigned short ushort_t;
typedef short short8 __attribute__((ext_vector_type(8)));
typedef float f32x4 __attribute__((ext_vector_type(4)));

__device__ __forceinline__ float blo(unsigned u) { return __uint_as_float(u << 16); }
__device__ __forceinline__ float bhi(unsigned u) { return __uint_as_float(u & 0xffff0000u); }
__device__ __forceinline__ float bf2f(ushort_t u) { return __uint_as_float((unsigned)u << 16); }
__device__ __forceinline__ ushort_t f2bfu(float f) {
    __hip_bfloat16 h = __float2bfloat16(f);
    return *reinterpret_cast<ushort_t*>(&h);
}
__device__ __forceinline__ unsigned pack2(float a, float b) {
    return (unsigned)f2bfu(a) | ((unsigned)f2bfu(b) << 16);
}
__device__ __forceinline__ float fast_tanh(float x) {
    // tanh(x) = 1 - 2/(exp(2x)+1); exact at +-inf, ~1e-6 abs err midrange
    return 1.f - 2.f / (__expf(2.f * x) + 1.f);
}

// -------- fused: bin histogram (blocks 0..255) + 4x weight transpose --------
__global__ __launch_bounds__(512) void count_transpose_kernel(
    const int* __restrict__ ei, int* __restrict__ bincount, int ne,
    const float* __restrict__ Wa, const float* __restrict__ Wb,
    const float* __restrict__ Wc, const float* __restrict__ Wd,
    ushort_t* __restrict__ Ta, ushort_t* __restrict__ Tb,
    ushort_t* __restrict__ Tc, ushort_t* __restrict__ Td) {
    __shared__ int h[NBIN];
    __shared__ float tt[2][32][33];
    if (blockIdx.x < 256) {
        for (int i = threadIdx.x; i < NBIN; i += 512) h[i] = 0;
        __syncthreads();
        const int stride = 256 * 512;
        for (int e = blockIdx.x * 512 + threadIdx.x; e < ne; e += stride)
            atomicAdd(&h[ei[(size_t)ne + e] >> 5], 1);
        __syncthreads();
        for (int i = threadIdx.x; i < NBIN; i += 512) {
            int c = h[i];
            if (c) atomicAdd(&bincount[i], c);
        }
    } else {
        int tile = (blockIdx.x - 256) * 2 + (threadIdx.x >> 8);
        int which = tile >> 6, rem = tile & 63;
        int bx = (rem & 7) << 5, by = (rem >> 3) << 5;
        const float* W = (which == 0) ? Wa : (which == 1) ? Wb
                        : (which == 2) ? Wc : Wd;
        ushort_t* Wt = (which == 0) ? Ta : (which == 1) ? Tb
                      : (which == 2) ? Tc : Td;
        int hf = threadIdx.x >> 8;
        int ltid = threadIdx.x & 255;
        int lx = ltid & 31, ly = ltid >> 5;
        #pragma unroll
        for (int i = 0; i < 32; i += 8)
            tt[hf][ly + i][lx] = W[(size_t)(by + ly + i) * 256 + bx + lx];
        __syncthreads();
        #pragma unroll
        for (int i = 0; i < 32; i += 8)
            Wt[(size_t)(bx + ly + i) * 256 + by + lx] = f2bfu(tt[hf][lx][ly + i]);
    }
}

__global__ __launch_bounds__(64) void bin_scan_kernel(
    const int* __restrict__ bincount, int* __restrict__ binstart,
    int* __restrict__ bincursor, int* __restrict__ rp, int ne, int nn) {
    __shared__ int carry;
    int lane = threadIdx.x;
    if (lane == 0) carry = 0;
    __syncthreads();
    for (int base = 0; base < NBIN; base += 64) {
        int i = base + lane;
        int v = (i < NBIN) ? bincount[i] : 0;
        int x = v;
        #pragma unroll
        for (int d = 1; d < 64; d <<= 1) {
            int y = __shfl_up(x, (unsigned)d, 64);
            if (lane >= d) x += y;
        }
        int c = carry;
        if (i < NBIN) { int ex = c + x - v; binstart[i] = ex; bincursor[i] = ex; }
        __syncthreads();
        if (lane == 63) carry = c + x;
        __syncthreads();
    }
    if (lane == 0) { binstart[NBIN] = ne; rp[nn] = ne; }
}

// -------- fused: partition (blocks 0..255) + gemm_f32a (blocks 256..1037) ---
__global__ __launch_bounds__(512) void part_gemm_kernel(
    const int* __restrict__ ei, const float* __restrict__ ew,
    int* __restrict__ bincursor, uint2* __restrict__ ptmp, int ne,
    const float* __restrict__ Af, const ushort_t* __restrict__ Wt,
    ushort_t* __restrict__ out, int nvalid) {
    __shared__ int h[NBIN];
    __shared__ int base_[NBIN];
    __shared__ __align__(16) ushort_t As[128 * 32];
    __shared__ __align__(16) ushort_t Bs[256 * 32];
    const int tid = threadIdx.x;
    if (blockIdx.x < 256) {
        for (int i = tid; i < NBIN; i += 512) h[i] = 0;
        __syncthreads();
        const int stride = 256 * 512;
        for (int e = blockIdx.x * 512 + tid; e < ne; e += stride)
            atomicAdd(&h[ei[(size_t)ne + e] >> 5], 1);
        __syncthreads();
        for (int i = tid; i < NBIN; i += 512) {
            int c = h[i];
            base_[i] = c ? atomicAdd(&bincursor[i], c) : 0;
            h[i] = 0;
        }
        __syncthreads();
        for (int e = blockIdx.x * 512 + tid; e < ne; e += stride) {
            int dd = ei[(size_t)ne + e];
            int ss = ei[e];
            float w = ew[e];
            int bin = dd >> 5;
            int r = atomicAdd(&h[bin], 1);
            ptmp[base_[bin] + r] =
                make_uint2((unsigned)ss | ((unsigned)(dd & 31) << 17),
                           __float_as_uint(w));
        }
        return;
    }
    const int gbid = blockIdx.x - 256;
    const int lane = tid & 63;
    const int wv = tid >> 6;
    const int wr = wv >> 2, wc = wv & 3;
    const size_t brow = (size_t)gbid * 128;

    const int ra = tid >> 2, ca = tid & 3;
    const int rb1 = ra + 128;
    const int csa = ca ^ ((ra >> 1) & 3);
    const int arow = (int)brow + ra;
    const bool aval = arow < nvalid;
    const float* gAf = Af + (size_t)arow * 256 + ca * 8;
    const ushort_t* gB0 = Wt + (size_t)ra  * 256 + ca * 8;
    const ushort_t* gB1 = Wt + (size_t)rb1 * 256 + ca * 8;
    ushort_t* lA  = As + ra * 32 + csa * 8;
    ushort_t* lB0 = Bs + ra * 32 + csa * 8;
    ushort_t* lB1 = Bs + rb1 * 32 + csa * 8;

    const int g = lane >> 4, rl = lane & 15;
    int aoff[4], boff[4];
    #pragma unroll
    for (int m = 0; m < 4; ++m) {
        int row = wr * 64 + m * 16 + rl;
        aoff[m] = row * 32 + (g ^ ((row >> 1) & 3)) * 8;
    }
    #pragma unroll
    for (int n = 0; n < 4; ++n) {
        int row = wc * 64 + n * 16 + rl;
        boff[n] = row * 32 + (g ^ ((row >> 1) & 3)) * 8;
    }

    f32x4 acc[4][4] = {};
    float4 pa0 = make_float4(0.f, 0.f, 0.f, 0.f), pa1 = pa0;
    if (aval) { pa0 = *(const float4*)gAf; pa1 = *(const float4*)(gAf + 4); }
    uint4 vb0 = *(const uint4*)gB0;
    uint4 vb1 = *(const uint4*)gB1;

    for (int ks = 0; ks < 8; ++ks) {
        uint4 va;
        va.x = pack2(pa0.x, pa0.y); va.y = pack2(pa0.z, pa0.w);
        va.z = pack2(pa1.x, pa1.y); va.w = pack2(pa1.z, pa1.w);
        *(uint4*)lA = va; *(uint4*)lB0 = vb0; *(uint4*)lB1 = vb1;
        __syncthreads();
        if (ks < 7) {
            int k0 = (ks + 1) * 32;
            if (aval) {
                pa0 = *(const float4*)(gAf + k0);
                pa1 = *(const float4*)(gAf + k0 + 4);
            }
            vb0 = *(const uint4*)(gB0 + k0);
            vb1 = *(const uint4*)(gB1 + k0);
        }
        short8 af[4], bfv[4];
        #pragma unroll
        for (int m = 0; m < 4; ++m) af[m] = *(const short8*)(As + aoff[m]);
        #pragma unroll
        for (int n = 0; n < 4; ++n) bfv[n] = *(const short8*)(Bs + boff[n]);
        #pragma unroll
        for (int m = 0; m < 4; ++m)
            #pragma unroll
            for (int n = 0; n < 4; ++n)
                acc[m][n] = __builtin_amdgcn_mfma_f32_16x16x32_bf16(
                    af[m], bfv[n], acc[m][n], 0, 0, 0);
        __syncthreads();
    }

    #pragma unroll
    for (int m = 0; m < 4; ++m) {
        #pragma unroll
        for (int r = 0; r < 4; ++r) {
            size_t row = brow + wr * 64 + m * 16 + g * 4 + r;
            #pragma unroll
            for (int n = 0; n < 4; ++n) {
                int col = wc * 64 + n * 16 + rl;
                out[row * 256 + col] = f2bfu(acc[m][n][r]);
            }
        }
    }
}

// within-bin counting sort -> dst-sorted (src,w) + rp[] CSR
__global__ __launch_bounds__(256) void binsort_kernel(
    const uint2* __restrict__ ptmp, const int* __restrict__ binstart,
    uint2* __restrict__ epair, int* __restrict__ rp) {
    int b = blockIdx.x;
    int tid = threadIdx.x;
    int beg = binstart[b], end = binstart[b + 1];
    int nE = end - beg;
    __shared__ uint2 sbuf[SORTCAP];
    __shared__ int cnt[BINB];
    __shared__ int cur[BINB];
    if (tid < BINB) cnt[tid] = 0;
    __syncthreads();
    if (nE <= SORTCAP) {
        for (int i = tid; i < nE; i += 256) {
            uint2 p = ptmp[beg + i];
            sbuf[i] = p;
            atomicAdd(&cnt[(p.x >> 17) & 31], 1);
        }
        __syncthreads();
        if (tid < BINB) {
            int v = cnt[tid];
            int x = v;
            #pragma unroll
            for (int d = 1; d < BINB; d <<= 1) {
                int y = __shfl_up(x, (unsigned)d, BINB);
                if (tid >= d) x += y;
            }
            int start = beg + x - v;
            cur[tid] = start;
            rp[b * BINB + tid] = start;
        }
        __syncthreads();
        for (int i = tid; i < nE; i += 256) {
            uint2 p = sbuf[i];
            int dl = (p.x >> 17) & 31;
            int pos = atomicAdd(&cur[dl], 1);
            epair[pos] = make_uint2(p.x & 0x1FFFF, p.y);
        }
    } else {  // global fallback (statistically never taken)
        for (int i = beg + tid; i < end; i += 256)
            atomicAdd(&cnt[(ptmp[i].x >> 17) & 31], 1);
        __syncthreads();
        if (tid < BINB) {
            int v = cnt[tid];
            int x = v;
            #pragma unroll
            for (int d = 1; d < BINB; d <<= 1) {
                int y = __shfl_up(x, (unsigned)d, BINB);
                if (tid >= d) x += y;
            }
            int start = beg + x - v;
            cur[tid] = start;
            rp[b * BINB + tid] = start;
        }
        __syncthreads();
        for (int i = beg + tid; i < end; i += 256) {
            uint2 p = ptmp[i];
            int dl = (p.x >> 17) & 31;
            int pos = atomicAdd(&cur[dl], 1);
            epair[pos] = make_uint2(p.x & 0x1FFFF, p.y);
        }
    }
}

// ---------------- weighted aggregation over bf16 rows (final form) ---------
__device__ __forceinline__ void acc8(float* a, uint4 v, float w) {
    a[0] += w * blo(v.x); a[1] += w * bhi(v.x);
    a[2] += w * blo(v.y); a[3] += w * bhi(v.y);
    a[4] += w * blo(v.z); a[5] += w * bhi(v.z);
    a[6] += w * blo(v.w); a[7] += w * bhi(v.w);
}

template<int ACT>
__global__ __launch_bounds__(256) void agg_bf16_kernel(
    const ushort_t* __restrict__ x, const int* __restrict__ rp,
    const uint2* __restrict__ ep, const float* __restrict__ bias,
    ushort_t* __restrict__ out, int n) {
    int wv = (int)(((size_t)blockIdx.x * blockDim.x + threadIdx.x) >> 6);
    int lane = threadIdx.x & 63;
    if (wv >= n) return;
    int half = lane >> 5;
    int l32 = lane & 31;
    int beg = rp[wv], end = rp[wv + 1];
    float a[8] = {};
    int e = beg;
    for (; e + 16 <= end; e += 16) {
        uint2 p0 = ep[e + half];
        uint2 p1 = ep[e + 2 + half];
        uint2 p2 = ep[e + 4 + half];
        uint2 p3 = ep[e + 6 + half];
        uint2 p4 = ep[e + 8 + half];
        uint2 p5 = ep[e + 10 + half];
        uint2 p6 = ep[e + 12 + half];
        uint2 p7 = ep[e + 14 + half];
        uint4 v0 = ((const uint4*)(x + (size_t)p0.x * D))[l32];
        uint4 v1 = ((const uint4*)(x + (size_t)p1.x * D))[l32];
        uint4 v2 = ((const uint4*)(x + (size_t)p2.x * D))[l32];
        uint4 v3 = ((const uint4*)(x + (size_t)p3.x * D))[l32];
        uint4 v4 = ((const uint4*)(x + (size_t)p4.x * D))[l32];
        uint4 v5 = ((const uint4*)(x + (size_t)p5.x * D))[l32];
        uint4 v6 = ((const uint4*)(x + (size_t)p6.x * D))[l32];
        uint4 v7 = ((const uint4*)(x + (size_t)p7.x * D))[l32];
        acc8(a, v0, __uint_as_float(p0.y));
        acc8(a, v1, __uint_as_float(p1.y));
        acc8(a, v2, __uint_as_float(p2.y));
        acc8(a, v3, __uint_as_float(p3.y));
        acc8(a, v4, __uint_as_float(p4.y));
        acc8(a, v5, __uint_as_float(p5.y));
        acc8(a, v6, __uint_as_float(p6.y));
        acc8(a, v7, __uint_as_float(p7.y));
    }
    for (; e + 4 <= end; e += 4) {
        uint2 p0 = ep[e + half];
        uint2 p1 = ep[e + 2 + half];
        uint4 v0 = ((const uint4*)(x + (size_t)p0.x * D))[l32];
        uint4 v1 = ((const uint4*)(x + (size_t)p1.x * D))[l32];
        acc8(a, v0, __uint_as_float(p0.y));
        acc8(a, v1, __uint_as_float(p1.y));
    }
    for (; e + 2 <= end; e += 2) {
        uint2 p0 = ep[e + half];
        uint4 v0 = ((const uint4*)(x + (size_t)p0.x * D))[l32];
        acc8(a, v0, __uint_as_float(p0.y));
    }
    if (e < end) {
        uint2 p0 = ep[e];
        uint4 v0 = ((const uint4*)(x + (size_t)p0.x * D))[l32];
        acc8(a, v0, half ? 0.f : __uint_as_float(p0.y));
    }
    #pragma unroll
    for (int j = 0; j < 8; ++j) a[j] += __shfl_xor(a[j], 32, 64);
    if (half == 0) {
        float4 b0 = ((const float4*)bias)[l32 * 2];
        float4 b1 = ((const float4*)bias)[l32 * 2 + 1];
        a[0] += b0.x; a[1] += b0.y; a[2] += b0.z; a[3] += b0.w;
        a[4] += b1.x; a[5] += b1.y; a[6] += b1.z; a[7] += b1.w;
        if (ACT == 1) {
            #pragma unroll
            for (int j = 0; j < 8; ++j) a[j] = fmaxf(a[j], 0.f);
        }
        uint4 o;
        o.x = pack2(a[0], a[1]); o.y = pack2(a[2], a[3]);
        o.z = pack2(a[4], a[5]); o.w = pack2(a[6], a[7]);
        ((uint4*)(out + (size_t)wv * D))[l32] = o;
    }
}

// ---------------- bf16 MFMA GEMM: MODE 1 plain, MODE 2 tanh-dot -------
template<int MODE>
__global__ __launch_bounds__(512) void mfma_gemm_kernel(
    const ushort_t* __restrict__ A, const ushort_t* __restrict__ Wt,
    const float* __restrict__ bias, ushort_t* __restrict__ out,
    const float* __restrict__ u, float* __restrict__ tout, int mvalid) {
    __shared__ __align__(16) ushort_t As[128 * 32];
    __shared__ __align__(16) ushort_t Bs[256 * 32];
    __shared__ float s_t[128];
    const int tid = threadIdx.x;
    const int lane = tid & 63;
    const int wv = tid >> 6;
    const int wr = wv >> 2, wc = wv & 3;
    const size_t brow = (size_t)blockIdx.x * 128;

    const int ra = tid >> 2, ca = tid & 3;
    const int rb1 = ra + 128;
    const int csa = ca ^ ((ra >> 1) & 3);
    const ushort_t* gA  = A  + (brow + ra) * 256 + ca * 8;
    const ushort_t* gB0 = Wt + (size_t)ra  * 256 + ca * 8;
    const ushort_t* gB1 = Wt + (size_t)rb1 * 256 + ca * 8;
    ushort_t* lA  = As + ra * 32 + csa * 8;
    ushort_t* lB0 = Bs + ra * 32 + csa * 8;
    ushort_t* lB1 = Bs + rb1 * 32 + csa * 8;

    const int g = lane >> 4, rl = lane & 15;
    int aoff[4], boff[4];
    #pragma unroll
    for (int m = 0; m < 4; ++m) {
        int row = wr * 64 + m * 16 + rl;
        aoff[m] = row * 32 + (g ^ ((row >> 1) & 3)) * 8;
    }
    #pragma unroll
    for (int n = 0; n < 4; ++n) {
        int row = wc * 64 + n * 16 + rl;
        boff[n] = row * 32 + (g ^ ((row >> 1) & 3)) * 8;
    }

    if (MODE == 2 && tid < 128) s_t[tid] = 0.f;

    f32x4 acc[4][4] = {};
    uint4 va  = *(const uint4*)gA;
    uint4 vb0 = *(const uint4*)gB0;
    uint4 vb1 = *(const uint4*)gB1;

    for (int ks = 0; ks < 8; ++ks) {
        *(uint4*)lA = va; *(uint4*)lB0 = vb0; *(uint4*)lB1 = vb1;
        __syncthreads();
        if (ks < 7) {
            int k0 = (ks + 1) * 32;
            va  = *(const uint4*)(gA + k0);
            vb0 = *(const uint4*)(gB0 + k0);
            vb1 = *(const uint4*)(gB1 + k0);
        }
        short8 af[4], bfv[4];
        #pragma unroll
        for (int m = 0; m < 4; ++m) af[m] = *(const short8*)(As + aoff[m]);
        #pragma unroll
        for (int n = 0; n < 4; ++n) bfv[n] = *(const short8*)(Bs + boff[n]);
        #pragma unroll
        for (int m = 0; m < 4; ++m)
            #pragma unroll
            for (int n = 0; n < 4; ++n)
                acc[m][n] = __builtin_amdgcn_mfma_f32_16x16x32_bf16(
                    af[m], bfv[n], acc[m][n], 0, 0, 0);
        __syncthreads();
    }

    if (MODE == 2) {
        float uvv[4];
        #pragma unroll
        for (int n = 0; n < 4; ++n) uvv[n] = u[wc * 64 + n * 16 + rl];
        #pragma unroll
        for (int m = 0; m < 4; ++m) {
            #pragma unroll
            for (int r = 0; r < 4; ++r) {
                float v = 0.f;
                #pragma unroll
                for (int n = 0; n < 4; ++n) v += fast_tanh(acc[m][n][r]) * uvv[n];
                v += __shfl_xor(v, 1, 64);
                v += __shfl_xor(v, 2, 64);
                v += __shfl_xor(v, 4, 64);
                v += __shfl_xor(v, 8, 64);
                if (rl == 0) atomicAdd(&s_t[wr * 64 + m * 16 + g * 4 + r], v);
            }
        }
        __syncthreads();
        if (tid < 128 && brow + tid < (size_t)mvalid) tout[brow + tid] = s_t[tid];
    } else {
        #pragma unroll
        for (int m = 0; m < 4; ++m) {
            #pragma unroll
            for (int r = 0; r < 4; ++r) {
                size_t row = brow + wr * 64 + m * 16 + g * 4 + r;
                #pragma unroll
                for (int n = 0; n < 4; ++n) {
                    int col = wc * 64 + n * 16 + rl;
                    float v = acc[m][n][r] + (bias ? bias[col] : 0.f);
                    out[row * 256 + col] = f2bfu(v);
                }
            }
        }
    }
}

// ---------------- code attention (branchless gather) ----------------
__global__ __launch_bounds__(256) void code_attn_kernel(
    const int* __restrict__ codes, const float* __restrict__ t,
    const ushort_t* __restrict__ emb, ushort_t* __restrict__ vembB,
    int* __restrict__ vmask) {
    int bv = blockIdx.x;
    int tid = threadIdx.x;
    __shared__ int s_codes[CODES];
    __shared__ float s_av[CODES];
    __shared__ int s_valid;
    if (tid < 64) {
        int c = codes[(size_t)bv * CODES + tid];
        s_codes[tid] = c;
        float e = (c > 0) ? t[c] : NEG_INF;
        float m = e;
        #pragma unroll
        for (int d = 32; d; d >>= 1) m = fmaxf(m, __shfl_xor(m, d, 64));
        float ex = expf(e - m);   // invalid codes underflow to exactly 0
        float s = ex;
        #pragma unroll
        for (int d = 32; d; d >>= 1) s += __shfl_xor(s, d, 64);
        s_av[tid] = ex / s;
        if (tid == 0) s_valid = (m > -1e8f) ? 1 : 0;
    }
    __syncthreads();
    float acc = 0.f;
    #pragma unroll 8
    for (int c = 0; c < CODES; ++c)
        acc += s_av[c] * bf2f(emb[(size_t)s_codes[c] * D + tid]);
    int valid = s_valid;
    vembB[(size_t)bv * D + tid] = f2bfu(valid ? acc : 0.f);
    if (tid == 0) vmask[bv] = valid;
}

// -------- fused patient attention + 3-layer decoder (one block per patient)
__global__ __launch_bounds__(512) void patient_dec_kernel(
    const ushort_t* __restrict__ vembB, const float* __restrict__ epr,
    const int* __restrict__ vmask,
    const float* __restrict__ Wd1, const float* __restrict__ bd1,
    const float* __restrict__ Wd2, const float* __restrict__ bd2,
    const float* __restrict__ Wd3, const float* __restrict__ bd3,
    float* __restrict__ outp) {
    int b = blockIdx.x;
    int tid = threadIdx.x;
    __shared__ float s_ap[VIS];
    __shared__ float s_x[256];
    __shared__ float s_h1[512];
    __shared__ float s_h2[256];
    __shared__ int s_any;

    if (tid < 64) {
        float e = -3e38f;
        if (tid < VIS) e = vmask[b * VIS + tid] ? epr[b * VIS + tid] : NEG_INF;
        float m = e;
        #pragma unroll
        for (int d = 32; d; d >>= 1) m = fmaxf(m, __shfl_xor(m, d, 64));
        float ex = (tid < VIS) ? expf(e - m) : 0.f;
        float s = ex;
        #pragma unroll
        for (int d = 32; d; d >>= 1) s += __shfl_xor(s, d, 64);
        if (tid < VIS) s_ap[tid] = ex / s;
        if (tid == 0) s_any = (m > -1e8f) ? 1 : 0;
    }
    __syncthreads();
    if (tid < 256) {
        float acc = 0.f;
        for (int v = 0; v < VIS; ++v)
            acc += s_ap[v] * bf2f(vembB[((size_t)b * VIS + v) * D + tid]);
        s_x[tid] = s_any ? acc : 0.f;
    }
    __syncthreads();
    {   // h1 = relu(pemb @ Wd1 + bd1): 512 cols, one per thread
        float acc = bd1[tid];
        #pragma unroll 8
        for (int k = 0; k < 256; ++k)
            acc = fmaf(s_x[k], Wd1[(size_t)k * 512 + tid], acc);
        s_h1[tid] = fmaxf(acc, 0.f);
    }
    __syncthreads();
    if (tid < 256) {   // h2 = relu(h1 @ Wd2 + bd2): 256 cols
        float acc = bd2[tid];
        #pragma unroll 8
        for (int k = 0; k < 512; ++k)
            acc = fmaf(s_h1[k], Wd2[(size_t)k * 256 + tid], acc);
        s_h2[tid] = fmaxf(acc, 0.f);
    }
    __syncthreads();
    for (int j = tid; j < 1000; j += 512) {   // logits: 1000 cols
        float acc = bd3[j];
        #pragma unroll 8
        for (int k = 0; k < 256; ++k)
            acc = fmaf(s_h2[k], Wd3[(size_t)k * 1000 + j], acc);
        outp[(size_t)b * 1000 + j] = acc;
    }
}

extern "C" void kernel_launch(void* const* d_in, const int* in_sizes, int n_in,
                              void* d_out, int out_size, void* d_ws, size_t ws_size,
                              hipStream_t stream) {
    const int* edge_index    = (const int*)d_in[0];
    const float* edge_weight = (const float*)d_in[1];
    const int* codes         = (const int*)d_in[2];
    const float* node_emb    = (const float*)d_in[3];
    const float* W1 = (const float*)d_in[4];
    const float* b1 = (const float*)d_in[5];
    const float* W2 = (const float*)d_in[6];
    const float* b2 = (const float*)d_in[7];
    const float* Wv = (const float*)d_in[8];
    const float* uv = (const float*)d_in[9];
    const float* Wp = (const float*)d_in[10];
    const float* up = (const float*)d_in[11];
    const float* Wd1 = (const float*)d_in[12];
    const float* bd1 = (const float*)d_in[13];
    const float* Wd2 = (const float*)d_in[14];
    const float* bd2 = (const float*)d_in[15];
    const float* Wd3 = (const float*)d_in[16];
    const float* bd3 = (const float*)d_in[17];

    const int NE = in_sizes[1];          // 3,200,000
    const int NN = in_sizes[3] / D;      // 100,000

    char* ws = (char*)d_ws;
    size_t off = 0;
    auto alloc = [&](size_t bytes) -> void* {
        void* p = ws + off;
        off += (bytes + 255) & ~(size_t)255;
        return p;
    };
    ushort_t* zbuf = (ushort_t*)alloc((size_t)MPAD * D * 2);  // z1 / z2
    ushort_t* hbuf = (ushort_t*)alloc((size_t)MPAD * D * 2);  // h
    ushort_t* embB = (ushort_t*)alloc((size_t)MPAD * D * 2);  // emb (bf16)
    uint2* ptmp   = (uint2*)alloc((size_t)NE * 8);            // bin-partitioned
    uint2* epair  = (uint2*)alloc((size_t)NE * 8);            // dst-sorted (src,w)
    int* bincount = (int*)alloc((size_t)NBIN * 4);
    int* binstart = (int*)alloc((size_t)(NBIN + 1) * 4);
    int* bincursor= (int*)alloc((size_t)NBIN * 4);
    int* rp       = (int*)alloc((size_t)(NN + 1) * 4);
    ushort_t* W1t = (ushort_t*)alloc(256 * 256 * 2);
    ushort_t* W2t = (ushort_t*)alloc(256 * 256 * 2);
    ushort_t* Wvt = (ushort_t*)alloc(256 * 256 * 2);
    ushort_t* Wpt = (ushort_t*)alloc(256 * 256 * 2);
    float* tbuf  = (float*)alloc((size_t)NN * 4);
    ushort_t* vembB = (ushort_t*)alloc((size_t)BPAT * VIS * D * 2);
    int*   vmask = (int*)  alloc((size_t)BPAT * VIS * 4);
    float* epr   = (float*)alloc((size_t)BPAT * VIS * 4);
    (void)ws_size; (void)n_in; (void)out_size;

    const int ab = NN / 4;                    // one wave/row, 4 waves/block

    // --- CSR build + layer-1 GEMM (co-scheduled) ---
    hipMemsetAsync(bincount, 0, (size_t)NBIN * 4, stream);
    count_transpose_kernel<<<256 + 128, 512, 0, stream>>>(
        edge_index, bincount, NE, W1, W2, Wv, Wp, W1t, W2t, Wvt, Wpt);
    bin_scan_kernel<<<1, 64, 0, stream>>>(bincount, binstart, bincursor, rp, NE, NN);
    // fused: partition (blocks 0..255) + z1 = node_emb @ W1 (blocks 256..1037)
    part_gemm_kernel<<<256 + MPAD / 128, 512, 0, stream>>>(
        edge_index, edge_weight, bincursor, ptmp, NE,
        node_emb, W1t, zbuf, NN);
    binsort_kernel<<<NBIN, 256, 0, stream>>>(ptmp, binstart, epair, rp);

    // --- GCN layer 1 (agg of z1): h = relu(agg(z1) + b1) ---
    agg_bf16_kernel<1><<<ab, 256, 0, stream>>>(zbuf, rp, epair, b1, hbuf, NN);

    // --- GCN layer 2: z2 = h @ W2; emb = agg(z2) + b2 ---
    mfma_gemm_kernel<1><<<MPAD / 128, 512, 0, stream>>>(
        hbuf, W2t, nullptr, zbuf, nullptr, nullptr, 0);
    agg_bf16_kernel<0><<<ab, 256, 0, stream>>>(zbuf, rp, epair, b2, embB, NN);

    // --- fused per-node code score: t = tanh(emb @ Wv) @ uv ---
    mfma_gemm_kernel<2><<<MPAD / 128, 512, 0, stream>>>(
        embB, Wvt, nullptr, nullptr, uv, tbuf, NN);

    // --- code attention -> vemb (bf16) ---
    code_attn_kernel<<<BPAT * VIS, 256, 0, stream>>>(codes, tbuf, embB, vembB, vmask);

    // --- fused visit score: ep = tanh(vemb @ Wp) @ up  (3200 = 25*128 rows) ---
    mfma_gemm_kernel<2><<<BPAT * VIS / 128, 512, 0, stream>>>(
        vembB, Wpt, nullptr, nullptr, up, epr, BPAT * VIS);

    // --- fused patient attention + decoder MLP ---
    patient_dec_kernel<<<BPAT, 512, 0, stream>>>(
        vembB, epr, vmask, Wd1, bd1, Wd2, bd2, Wd3, bd3, (float*)d_out);
}